// Round 8
// baseline (125.713 us; speedup 1.0000x reference)
//
#include <hip/hip_runtime.h>
#include <math.h>

#define NCOLS 5000
#define NF4   1250            // NCOLS / 4
#define FIF   250             // float4 per fifth (1250 = 5*250, exact)
#define NFIF  5
#define BLOCK 256
#define NWAVES 4
#define TOPKK 10
#define TR    3               // threshold rounds/wave (4*3 >= 12 >= k)
#define CAP   64              // per-fifth candidate capacity (expect ~15-30)
#define OUTK  10              // exact top-k emitted per fifth per path

// ws layout (nrf = nrows*5):
//   sums : [nrf][8]   (nv, sq, sp, seyy, seyu, aspu, aspd, 0)
//   top  : [nrf][OUTK] float2 (key bits, u value), zero-padded
//   bot  : [nrf][OUTK] float2 (key bits, d value), zero-padded

__device__ __forceinline__ unsigned mono_f32(float f) {
  unsigned u = __float_as_uint(f);
  return (u & 0x80000000u) ? ~u : (u | 0x80000000u);
}
__device__ __forceinline__ float wave_sum_f(float v) {
#pragma unroll
  for (int o = 1; o < 64; o <<= 1) v += __shfl_xor(v, o);
  return v;
}
__device__ __forceinline__ int wave_sum_i(int v) {
#pragma unroll
  for (int o = 1; o < 64; o <<= 1) v += __shfl_xor(v, o);
  return v;
}
__device__ __forceinline__ unsigned wave_max_u(unsigned v) {
#pragma unroll
  for (int o = 1; o < 64; o <<= 1) {
    unsigned w = __shfl_xor(v, o);
    v = w > v ? w : v;
  }
  return v;
}

// ============================ PASS 1 =====================================
// Fill-shaped streaming: 5 blocks per row, 1 float4/thread/array, no LDS
// data staging, ~50 VGPRs, grid nrows*5 = 5120 -> 20 serial blocks/CU with
// 8 resident. Emits per-fifth sums + exact top-10/bottom-10 (key,value).
extern "C" __global__ __launch_bounds__(BLOCK, 8)
void part_kernel(const float* __restrict__ up, const float* __restrict__ down,
                 const float* __restrict__ yt, const int* __restrict__ masks,
                 float* __restrict__ ws_sums, float2* __restrict__ ws_top,
                 float2* __restrict__ ws_bot) {
  __shared__ float red_f[7][NWAVES];
  __shared__ unsigned t1w_t[NWAVES], t1w_b[NWAVES];
  __shared__ unsigned keys_t[CAP]; __shared__ float vals_t[CAP];
  __shared__ unsigned keys_b[CAP]; __shared__ float vals_b[CAP];
  __shared__ int ct, cb;

  const int tid = threadIdx.x;
  const int lane = tid & 63;
  const int wv = tid >> 6;
  const int bq = blockIdx.x;                  // row*5 + fifth
  const long long b4 = (long long)bq * FIF;   // row*1250 + fifth*250

  if (tid == 0) { ct = 0; cb = 0; }

  const bool inb = tid < FIF;
  const int fc = inb ? tid : FIF - 1;         // clamped; invalid via inb

  // ---- 4 independent vector loads (16 payload VGPRs, nothing to sink).
  const float4 y4 = ((const float4*)yt)[b4 + fc];
  const float4 u4 = ((const float4*)up)[b4 + fc];
  const float4 d4 = ((const float4*)down)[b4 + fc];
  const int4   m4 = ((const int4*)masks)[b4 + fc];

  int nv_l = 0;
  float sq = 0.f, sp = 0.f, seyy = 0.f, seyu = 0.f;
  float pu = 1.f, pd = 1.f;                   // grouped-softplus products
  unsigned tmax = 0u, tbmax = 0u;
  unsigned kk[4]; float ua[4], da[4];

#define ELEM(c, Y, U, D, M)                                             \
  {                                                                     \
    const bool valid = inb && ((M) > 0);                                \
    const float y = (Y), u = (U), d = (D);                              \
    const unsigned kd = valid ? mono_f32(y) : 0u;                       \
    const unsigned kb2 = valid ? ~kd : 0u;                              \
    kk[c] = kd; ua[c] = u; da[c] = d;                                   \
    tmax = kd > tmax ? kd : tmax;                                       \
    tbmax = kb2 > tbmax ? kb2 : tbmax;                                  \
    const float mf = valid ? 1.f : 0.f;                                 \
    const float ey = __expf(y);                                         \
    const float eu = __expf(u);                                         \
    const float ed = __expf(d);                                         \
    const float mey = mf * ey;                                          \
    nv_l += valid ? 1 : 0;                                              \
    sq += mey;                                                          \
    seyy = fmaf(mey, y, seyy);                                          \
    seyu = fmaf(mey, u, seyu);                                          \
    sp += mf * eu;                                                      \
    pu *= valid ? (1.f + eu) : 1.f;                                     \
    pd *= valid ? (1.f + ed) : 1.f;                                     \
  }

  ELEM(0, y4.x, u4.x, d4.x, m4.x)
  ELEM(1, y4.y, u4.y, d4.y, m4.y)
  ELEM(2, y4.z, u4.z, d4.z, m4.z)
  ELEM(3, y4.w, u4.w, d4.w, m4.w)
#undef ELEM

  // One log per thread per path (grouped softplus; <=4 factors, each
  // <= 1+e^|x|max, fp32-safe for |x| up to ~20; inputs ~N(0,1)).
  const float aspu = __logf(pu);
  const float aspd = __logf(pd);

  // ---- Wave reduces (7 independent chains; compiler interleaves).
  nv_l = wave_sum_i(nv_l);
  sq = wave_sum_f(sq);
  sp = wave_sum_f(sp);
  seyy = wave_sum_f(seyy);
  seyu = wave_sum_f(seyu);
  const float au = wave_sum_f(aspu);
  const float ad = wave_sum_f(aspd);

  // ---- Per-wave TR=3 thresholds (top/bottom interleaved).
  unsigned t1t = 0u, t1b_ = 0u;
  {
    unsigned vt = tmax, vb = tbmax;
#pragma unroll
    for (int r = 0; r < TR; ++r) {
      const unsigned mt = wave_max_u(vt);
      const unsigned mb_ = wave_max_u(vb);
      if (vt == mt) vt = 0u;
      if (vb == mb_) vb = 0u;
      t1t = mt; t1b_ = mb_;
    }
  }
  if (lane == 0) {
    red_f[0][wv] = (float)nv_l;
    red_f[1][wv] = sq;  red_f[2][wv] = sp;
    red_f[3][wv] = seyy; red_f[4][wv] = seyu;
    red_f[5][wv] = au;  red_f[6][wv] = ad;
    t1w_t[wv] = t1t; t1w_b[wv] = t1b_;
  }
  __syncthreads();

  // Block threshold: min over 4 waves of per-wave 3rd-largest thread-max
  // -> >= 12 >= k candidates survive (waves with <3 valid threads yield 0
  // -> admit all valid; probabilistically negligible and still correct).
  unsigned t1 = t1w_t[0], t1b = t1w_b[0];
#pragma unroll
  for (int w = 1; w < NWAVES; ++w) {
    t1 = t1w_t[w] < t1 ? t1w_t[w] : t1;
    t1b = t1w_b[w] < t1b ? t1w_b[w] : t1b;
  }
  const int nv_q = (int)(red_f[0][0] + red_f[0][1] + red_f[0][2] + red_f[0][3]);

  // ---- Compact candidates (values carried; no reload ever).
#pragma unroll
  for (int c = 0; c < 4; ++c) {
    const unsigned kd = kk[c];
    if (kd != 0u) {
      if (kd >= t1) {
        const int i = atomicAdd(&ct, 1);
        if (i < CAP) { keys_t[i] = kd; vals_t[i] = ua[c]; }
      }
      const unsigned kb2 = ~kd;
      if (kb2 >= t1b) {
        const int i = atomicAdd(&cb, 1);
        if (i < CAP) { keys_b[i] = kb2; vals_b[i] = da[c]; }
      }
    }
  }
  __syncthreads();

  // ---- Parallel tails: wv0 = exact top-10, wv1 = bottom-10, wv2 = sums.
  const int kq = nv_q < TOPKK ? nv_q : TOPKK;
  if (wv == 0) {
    const int n = ct < CAP ? ct : CAP;
    const unsigned kc = (lane < n) ? keys_t[lane] : 0u;
    unsigned thr = 0u;
#pragma unroll
    for (int bb = 31; bb >= 0; --bb) {
      const unsigned t = thr | (1u << bb);
      thr = (__popcll(__ballot(kc >= t)) >= kq) ? t : thr;
    }
    const bool sel = (kc >= thr) && (kc != 0u);
    const unsigned long long msk = __ballot(sel);
    const int idx = __popcll(msk & ((1ull << lane) - 1ull));
    if (sel && idx < OUTK)
      ws_top[bq * OUTK + idx] = make_float2(__uint_as_float(kc), vals_t[lane]);
    int cnt = __popcll(msk);
    cnt = cnt < OUTK ? cnt : OUTK;
    if (lane >= cnt && lane < OUTK)
      ws_top[bq * OUTK + lane] = make_float2(0.f, 0.f);
  } else if (wv == 1) {
    const int n = cb < CAP ? cb : CAP;
    const unsigned kc = (lane < n) ? keys_b[lane] : 0u;
    unsigned thr = 0u;
#pragma unroll
    for (int bb = 31; bb >= 0; --bb) {
      const unsigned t = thr | (1u << bb);
      thr = (__popcll(__ballot(kc >= t)) >= kq) ? t : thr;
    }
    const bool sel = (kc >= thr) && (kc != 0u);
    const unsigned long long msk = __ballot(sel);
    const int idx = __popcll(msk & ((1ull << lane) - 1ull));
    if (sel && idx < OUTK)
      ws_bot[bq * OUTK + idx] = make_float2(__uint_as_float(kc), vals_b[lane]);
    int cnt = __popcll(msk);
    cnt = cnt < OUTK ? cnt : OUTK;
    if (lane >= cnt && lane < OUTK)
      ws_bot[bq * OUTK + lane] = make_float2(0.f, 0.f);
  } else if (wv == 2 && lane < 8) {
    const float s = (lane < 7)
        ? red_f[lane][0] + red_f[lane][1] + red_f[lane][2] + red_f[lane][3]
        : 0.f;
    ws_sums[bq * 8 + lane] = s;
  }
}

// ============================ PASS 2 =====================================
// One wave per row: fold 5 fifths' sums (40 floats), merge 5x10 candidates
// per path (row top-10 is a subset), ballot search, loss, block atomicAdd.
extern "C" __global__ __launch_bounds__(256, 8)
void finish_kernel(const float* __restrict__ ws_sums,
                   const float2* __restrict__ ws_top,
                   const float2* __restrict__ ws_bot,
                   float* __restrict__ out, int nrows, float inv_nrows) {
  __shared__ float wl[NWAVES];
  const int tid = threadIdx.x;
  const int lane = tid & 63;
  const int wv = tid >> 6;
  const int row = blockIdx.x * NWAVES + wv;

  float loss = 0.f;
  if (row < nrows) {
    // 40 contiguous sums; fold fifths with 4 shfls (lanes 0..7 get S_i).
    const float v = (lane < 40) ? ws_sums[row * 40 + lane] : 0.f;
    float s = v;
    s += __shfl(v, (lane + 8) & 63);
    s += __shfl(v, (lane + 16) & 63);
    s += __shfl(v, (lane + 24) & 63);
    s += __shfl(v, (lane + 32) & 63);
    const float nvf = __shfl(s, 0);
    const int nv = (int)nvf;
    if (nv > 0) {
      const int k = nv < TOPKK ? nv : TOPKK;
      const float2 a  = (lane < 50) ? ws_top[row * 50 + lane] : make_float2(0.f, 0.f);
      const float2 b2 = (lane < 50) ? ws_bot[row * 50 + lane] : make_float2(0.f, 0.f);
      const unsigned kt = __float_as_uint(a.x);
      const unsigned kb = __float_as_uint(b2.x);
      unsigned thr_t = 0u, thr_b = 0u;
#pragma unroll
      for (int bb = 31; bb >= 0; --bb) {
        const unsigned tt = thr_t | (1u << bb);
        const unsigned tb = thr_b | (1u << bb);
        thr_t = (__popcll(__ballot(kt >= tt)) >= k) ? tt : thr_t;
        thr_b = (__popcll(__ballot(kb >= tb)) >= k) ? tb : thr_b;
      }
      const float su = wave_sum_f((kt >= thr_t && kt != 0u) ? a.y : 0.f);
      const float sd = wave_sum_f((kb >= thr_b && kb != 0u) ? b2.y : 0.f);
      const float SQ = __shfl(s, 1), SP = __shfl(s, 2);
      const float SYY = __shfl(s, 3), SYU = __shfl(s, 4);
      const float ASU = __shfl(s, 5), ASD = __shfl(s, 6);
      // KL closed form: sum q*(logq-logp) = (Seyy-Seyu)/Sq - log(Sq) + log(Sp)
      const float kl = (SYY - SYU) / SQ - __logf(SQ) + __logf(SP);
      loss = ((ASU - su) + 0.5f * (ASD - sd) + 0.3f * kl) / nvf;
    }
  }
  if (lane == 0) wl[wv] = loss;
  __syncthreads();
  if (tid == 0)
    atomicAdd(out, (wl[0] + wl[1] + wl[2] + wl[3]) * inv_nrows);
}

extern "C" void kernel_launch(void* const* d_in, const int* in_sizes, int n_in,
                              void* d_out, int out_size, void* d_ws, size_t ws_size,
                              hipStream_t stream) {
  const float* up_logits   = (const float*)d_in[0];
  const float* down_logits = (const float*)d_in[1];
  const float* y_true      = (const float*)d_in[2];
  const int*   masks       = (const int*)d_in[3];

  const int nrows = in_sizes[0] / NCOLS;
  const int nrf = nrows * NFIF;

  float* wsf = (float*)d_ws;
  float* ws_sums = wsf;                                  // nrf*8 floats
  float2* ws_top = (float2*)(wsf + (size_t)nrf * 8);     // nrf*OUTK float2
  float2* ws_bot = ws_top + (size_t)nrf * OUTK;          // nrf*OUTK float2
  (void)ws_size;

  hipMemsetAsync(d_out, 0, sizeof(float) * (size_t)out_size, stream);
  part_kernel<<<nrf, BLOCK, 0, stream>>>(up_logits, down_logits, y_true, masks,
                                         ws_sums, ws_top, ws_bot);
  finish_kernel<<<(nrows + NWAVES - 1) / NWAVES, 256, 0, stream>>>(
      ws_sums, ws_top, ws_bot, (float*)d_out, nrows, 1.0f / (float)nrows);
}

// Round 9
// 115.279 us; speedup vs baseline: 1.0905x; 1.0905x over previous
//
#include <hip/hip_runtime.h>
#include <math.h>

#define NCOLS 5000
#define NF4   1250            // NCOLS / 4
#define BLOCK 256
#define NWAVES (BLOCK / 64)
#define NITER 5               // ceil(NF4 / BLOCK)
#define TOPKK 10
#define TR    3               // ceil(TOPKK / NWAVES) threshold rounds per wave
#define CAP 128               // candidate capacity (expected ~20-40/block)

// Monotone-ascending mapping float -> uint32 (total order on finite floats).
__device__ __forceinline__ unsigned mono_f32(float f) {
  unsigned u = __float_as_uint(f);
  return (u & 0x80000000u) ? ~u : (u | 0x80000000u);
}

__device__ __forceinline__ float wave_sum_f(float v) {
#pragma unroll
  for (int o = 1; o < 64; o <<= 1) v += __shfl_xor(v, o);
  return v;
}
__device__ __forceinline__ int wave_sum_i(int v) {
#pragma unroll
  for (int o = 1; o < 64; o <<= 1) v += __shfl_xor(v, o);
  return v;
}
__device__ __forceinline__ unsigned wave_max_u(unsigned v) {
#pragma unroll
  for (int o = 1; o < 64; o <<= 1) {
    unsigned w = __shfl_xor(v, o);
    v = w > v ? w : v;
  }
  return v;
}

// use_ws != 0 : plain store of per-row loss to ws[row]; reducer kernel sums.
// use_ws == 0 : legacy atomicAdd fallback (workspace too small).
extern "C" __global__ __launch_bounds__(BLOCK, 4)
void row_loss_kernel(const float* __restrict__ up, const float* __restrict__ down,
                     const float* __restrict__ yt, const int* __restrict__ masks,
                     float* __restrict__ ws, float* __restrict__ out,
                     float inv_nrows, int use_ws) {
  __shared__ uint4 km_s[NITER * BLOCK];  // 20 KB per-thread-private key slots
  __shared__ float red_f[6][NWAVES];   // sq, sp, seyy, seyu, aspu, aspd
  __shared__ int red_i[NWAVES];        // nv partials
  __shared__ unsigned t1w_t[NWAVES];   // per-wave TR-th-largest thread-max (top)
  __shared__ unsigned t1w_b[NWAVES];   // same, bottom (~key space)
  __shared__ unsigned keys_t[CAP];     // top candidate keys
  __shared__ int      col_t[CAP];      // their column index
  __shared__ unsigned keys_b[CAP];     // bottom candidate keys (~key)
  __shared__ int      col_b[CAP];
  __shared__ int ct, cb;
  __shared__ float s_res[2];           // SU, SD

  const int tid = threadIdx.x;
  const int lane = tid & 63;
  const int wv = tid >> 6;
  const int row = blockIdx.x;
  const long long b4 = (long long)row * NF4;
  const long long base = (long long)row * NCOLS;

  const float4* up4 = (const float4*)up + b4;
  const float4* dn4 = (const float4*)down + b4;
  const float4* yt4 = (const float4*)yt + b4;
  const int4*   mk4 = (const int4*)masks + b4;

  if (tid == 0) { ct = 0; cb = 0; }

  // ---- 20 unconditional clamped vector loads, all issued upfront.
  float4 y4[NITER], u4[NITER], d4[NITER];
  int4 m4[NITER];
#pragma unroll
  for (int j = 0; j < NITER; ++j) {
    const int f = j * BLOCK + tid;
    const int fc = f < NF4 ? f : NF4 - 1;   // clamp, no branch around loads
    y4[j] = yt4[fc];
    u4[j] = up4[fc];
    d4[j] = dn4[fc];
    m4[j] = mk4[fc];
  }
  // Fence: forbid the scheduler from sinking the loads into the compute loop.
  __builtin_amdgcn_sched_barrier(0);

  // ---- Single data pass: scalar sums + per-thread max keys.
  int nv_l = 0;
  float sq = 0.f, sp = 0.f, seyy = 0.f, seyu = 0.f, aspu = 0.f, aspd = 0.f;
  unsigned tmax = 0u, tbmax = 0u;
#pragma unroll
  for (int j = 0; j < NITER; ++j) {
    const bool inb = (j * BLOCK + tid) < NF4;
    const float* yp = (const float*)&y4[j];
    const float* upp = (const float*)&u4[j];
    const float* dp = (const float*)&d4[j];
    const int* mp = (const int*)&m4[j];
    unsigned kk[4];
#pragma unroll
    for (int c = 0; c < 4; ++c) {
      const bool valid = inb && (mp[c] > 0);
      const float y = yp[c], u = upp[c], d = dp[c];
      const unsigned kd = valid ? mono_f32(y) : 0u;
      const unsigned kb = valid ? ~kd : 0u;
      kk[c] = kd;
      tmax = kd > tmax ? kd : tmax;
      tbmax = kb > tbmax ? kb : tbmax;
      if (valid) {
        nv_l++;
        const float ey = __expf(y);
        const float eu = __expf(u);   // reused: Sp and softplus(u)
        const float ed = __expf(d);
        sq += ey;
        seyy += ey * y;
        seyu += ey * u;
        sp += eu;
        aspu += (u > 15.f) ? u : __logf(1.f + eu);
        aspd += (d > 15.f) ? d : __logf(1.f + ed);
      }
    }
    km_s[j * BLOCK + tid] = make_uint4(kk[0], kk[1], kk[2], kk[3]);
  }

  // ---- Wave reduces of scalars.
  nv_l = wave_sum_i(nv_l);
  sq = wave_sum_f(sq);
  sp = wave_sum_f(sp);
  seyy = wave_sum_f(seyy);
  seyu = wave_sum_f(seyu);
  aspu = wave_sum_f(aspu);
  aspd = wave_sum_f(aspd);
  if (lane == 0) {
    red_i[wv] = nv_l;
    red_f[0][wv] = sq;  red_f[1][wv] = sp;
    red_f[2][wv] = seyy; red_f[3][wv] = seyu;
    red_f[4][wv] = aspu; red_f[5][wv] = aspd;
  }

  // ---- Per-wave filter threshold, TR=3 rounds.
  // TR-th-largest thread-max per wave; across NWAVES waves >= 12 >= TOPKK
  // elements >= min_w(t_w). Top and bottom chains interleave for ILP.
  {
    unsigned vt = tmax, vb = tbmax, t1t = 0u, t1b = 0u;
#pragma unroll
    for (int r = 0; r < TR; ++r) {
      unsigned mt = wave_max_u(vt);
      unsigned mb = wave_max_u(vb);
      if (vt == mt) vt = 0u;
      if (vb == mb) vb = 0u;
      t1t = mt; t1b = mb;
    }
    if (lane == 0) { t1w_t[wv] = t1t; t1w_b[wv] = t1b; }
  }
  __syncthreads();

  int nv = 0;
#pragma unroll
  for (int w = 0; w < NWAVES; ++w) nv += red_i[w];
  const int k = nv < TOPKK ? nv : TOPKK;

  unsigned t1 = 0xFFFFFFFFu, t1b = 0xFFFFFFFFu;
#pragma unroll
  for (int w = 0; w < NWAVES; ++w) {
    t1 = t1w_t[w] < t1 ? t1w_t[w] : t1;
    t1b = t1w_b[w] < t1b ? t1w_b[w] : t1b;
  }

  // ---- Compact candidate (key, column) pairs into LDS (~20-40 total).
#pragma unroll
  for (int j = 0; j < NITER; ++j) {
    const uint4 kk4 = km_s[j * BLOCK + tid];
    const unsigned ka[4] = {kk4.x, kk4.y, kk4.z, kk4.w};
#pragma unroll
    for (int c = 0; c < 4; ++c) {
      const unsigned kd = ka[c];
      if (kd != 0u) {
        const int col = ((j * BLOCK + tid) << 2) + c;
        if (kd >= t1) {
          int i = atomicAdd(&ct, 1);
          if (i < CAP) { keys_t[i] = kd; col_t[i] = col; }
        }
        const unsigned kb = ~kd;
        if (kb >= t1b) {
          int i = atomicAdd(&cb, 1);
          if (i < CAP) { keys_b[i] = kb; col_b[i] = col; }
        }
      }
    }
  }
  __syncthreads();

  // ---- Waves 0/1: exact k-th key via 32-step ballot binary search.
  if (wv == 0) {
    const int n = ct < CAP ? ct : CAP;
    const unsigned k0 = (lane < n) ? keys_t[lane] : 0u;
    const unsigned k1 = (64 + lane < n) ? keys_t[64 + lane] : 0u;
    unsigned thr = 0u;
#pragma unroll
    for (int b = 31; b >= 0; --b) {
      const unsigned t = thr | (1u << b);
      const int c = __popcll(__ballot(k0 >= t)) + __popcll(__ballot(k1 >= t));
      thr = (c >= k) ? t : thr;
    }
    float su = 0.f;
    if (k0 >= thr && k0 != 0u) su += up[base + col_t[lane]];
    if (k1 >= thr && k1 != 0u) su += up[base + col_t[64 + lane]];
    su = wave_sum_f(su);
    if (lane == 0) s_res[0] = su;
  } else if (wv == 1) {
    const int n = cb < CAP ? cb : CAP;
    const unsigned k0 = (lane < n) ? keys_b[lane] : 0u;
    const unsigned k1 = (64 + lane < n) ? keys_b[64 + lane] : 0u;
    unsigned thr = 0u;
#pragma unroll
    for (int b = 31; b >= 0; --b) {
      const unsigned t = thr | (1u << b);
      const int c = __popcll(__ballot(k0 >= t)) + __popcll(__ballot(k1 >= t));
      thr = (c >= k) ? t : thr;
    }
    float sd = 0.f;
    if (k0 >= thr && k0 != 0u) sd += down[base + col_b[lane]];
    if (k1 >= thr && k1 != 0u) sd += down[base + col_b[64 + lane]];
    sd = wave_sum_f(sd);
    if (lane == 0) s_res[1] = sd;
  }
  __syncthreads();

  if (tid == 0) {
    float loss = 0.f;
    if (nv > 0) {
      float SQ = 0.f, SP = 0.f, SYY = 0.f, SYU = 0.f, ASU = 0.f, ASD = 0.f;
#pragma unroll
      for (int w = 0; w < NWAVES; ++w) {
        SQ += red_f[0][w]; SP += red_f[1][w];
        SYY += red_f[2][w]; SYU += red_f[3][w];
        ASU += red_f[4][w]; ASD += red_f[5][w];
      }
      const float SU = s_res[0];
      const float SD = s_res[1];
      // KL closed form: sum q*(logq-logp) = (Seyy-Seyu)/Sq - log(Sq) + log(Sp)
      const float kl = (SYY - SYU) / SQ - __logf(SQ) + __logf(SP);
      const float up_loss = ASU - SU;  // sum softplus(u) - sum_{topk} u
      const float dn_loss = ASD - SD;  // sum softplus(d) - sum_{botk} d
      loss = (up_loss + 0.5f * dn_loss + 0.3f * kl) / (float)nv;
    }
    if (use_ws) {
      ws[row] = loss;                       // plain store, no serialization
    } else if (loss != 0.f) {
      atomicAdd(out, loss * inv_nrows);     // legacy fallback
    }
  }
}

// Deterministic 1-block tree reduction of the per-row losses.
extern "C" __global__ __launch_bounds__(256)
void reduce_loss_kernel(const float* __restrict__ ws, float* __restrict__ out,
                        int n, float inv_n) {
  __shared__ float part[4];
  const int tid = threadIdx.x;
  const int lane = tid & 63;
  const int wv = tid >> 6;
  float s = 0.f;
  const int n4 = n >> 2;
  const float4* w4 = (const float4*)ws;
  for (int i = tid; i < n4; i += 256) {
    const float4 v = w4[i];
    s += (v.x + v.y) + (v.z + v.w);
  }
  for (int i = (n4 << 2) + tid; i < n; i += 256) s += ws[i];
  s = wave_sum_f(s);
  if (lane == 0) part[wv] = s;
  __syncthreads();
  if (tid == 0) out[0] = (part[0] + part[1] + part[2] + part[3]) * inv_n;
}

extern "C" void kernel_launch(void* const* d_in, const int* in_sizes, int n_in,
                              void* d_out, int out_size, void* d_ws, size_t ws_size,
                              hipStream_t stream) {
  const float* up_logits   = (const float*)d_in[0];
  const float* down_logits = (const float*)d_in[1];
  const float* y_true      = (const float*)d_in[2];
  const int*   masks       = (const int*)d_in[3];

  const int nrows = in_sizes[0] / NCOLS;
  const int use_ws = (d_ws != nullptr && ws_size >= (size_t)nrows * sizeof(float)) ? 1 : 0;

  hipMemsetAsync(d_out, 0, sizeof(float) * (size_t)out_size, stream);
  row_loss_kernel<<<nrows, BLOCK, 0, stream>>>(up_logits, down_logits, y_true,
                                               masks, (float*)d_ws, (float*)d_out,
                                               1.0f / (float)nrows, use_ws);
  if (use_ws) {
    reduce_loss_kernel<<<1, 256, 0, stream>>>((const float*)d_ws, (float*)d_out,
                                              nrows, 1.0f / (float)nrows);
  }
}